// Round 5
// baseline (518.273 us; speedup 1.0000x reference)
//
#include <hip/hip_runtime.h>

#define N_NODES 50000
#define N_EDGES 800000
#define N_GRAPHS 512
#define HIDDEN 256
#define NODE_FEAT 9
#define LAYERS 4
#define BUCKET 64     // max degree capacity (mean 16, max ~35 for uniform random)
#define NSLICE 8      // 8 column slices of 32 -> one per XCD (L2-resident: 3.2 MB)

typedef float floatx4 __attribute__((ext_vector_type(4)));
typedef short short8 __attribute__((ext_vector_type(8)));

__device__ __forceinline__ float bf2f(unsigned u) {
    unsigned v = u << 16;
    float f;
    __builtin_memcpy(&f, &v, 4);
    return f;
}
__device__ __forceinline__ unsigned short f2bf(float f) {
    unsigned v;
    __builtin_memcpy(&v, &f, 4);
    v += 0x7FFFu + ((v >> 16) & 1u);   // round-to-nearest-even
    return (unsigned short)(v >> 16);
}
// slice-major element base: h[s][n][0..31], in ushorts
__device__ __forceinline__ size_t smb(int s, int n) {
    return ((size_t)s * N_NODES + (size_t)n) * 32;
}

// ---------------- one-pass bucketed CSR build (standalone: max TLP, 1 atomic/thread) ----------------
__global__ void fillb_kernel(const int* __restrict__ src, const int* __restrict__ dst,
                             int* __restrict__ cnt, int* __restrict__ col_src, int E) {
    int e = blockIdx.x * blockDim.x + threadIdx.x;
    if (e < E) {
        int d = dst[e];
        int pos = atomicAdd(&cnt[d], 1);
        if (pos < BUCKET) col_src[d * BUCKET + pos] = src[e];
    }
}

// ---------------- combined aux: dinv + graph boundary search ----------------
__global__ __launch_bounds__(256) void aux_kernel(const int* __restrict__ cnt,
                                                  float* __restrict__ dinv,
                                                  const int* __restrict__ batch,
                                                  int* __restrict__ gstart) {
    int i = blockIdx.x * 256 + threadIdx.x;
    if (i < N_NODES) dinv[i] = rsqrtf((float)(cnt[i] + 1));   // +1 self loop
    int g = i - N_NODES;
    if (g >= 0 && g <= N_GRAPHS) {
        if (g == N_GRAPHS) { gstart[g] = N_NODES; return; }
        int lo = 0, hi = N_NODES;
        while (lo < hi) {
            int mid = (lo + hi) >> 1;
            if (batch[mid] < g) lo = mid + 1; else hi = mid;
        }
        gstart[g] = lo;   // first node with batch[n] >= g
    }
}

// ---------------- W pre-pack into MFMA B-fragment layout (bf16) ----------------
__global__ __launch_bounds__(256) void packW_kernel(const float* __restrict__ W,
                                                    unsigned short* __restrict__ Wsw) {
    int idx = blockIdx.x * 256 + threadIdx.x;   // 0..32767
    int lane = idx & 63;
    int ct   = (idx >> 6) & 15;
    int ks   = (idx >> 10) & 7;
    int l    = idx >> 13;
    int n = ct * 16 + (lane & 15);
    int kbase = ks * 32 + (lane >> 4) * 8;
    const float* Wl = W + (size_t)l * HIDDEN * HIDDEN;
    alignas(16) unsigned short tmp[8];
    #pragma unroll
    for (int j = 0; j < 8; j++)
        tmp[j] = f2bf(Wl[(size_t)(kbase + j) * HIDDEN + n]);
    *(uint4*)&Wsw[(size_t)idx * 8] = *(const uint4*)tmp;
}

// ---------------- fused embed + gemm1 (slice-major C-store) ----------------
__global__ __launch_bounds__(256, 3) void embed_gemm(const float* __restrict__ x,
                                                     const float* __restrict__ embW,
                                                     const float* __restrict__ embb,
                                                     const unsigned short* __restrict__ Wsw,
                                                     unsigned short* __restrict__ hwout, int N) {
    __shared__ unsigned short As[64][264];   // +8 pad; reused as C-buffer in epilogue
    int t = threadIdx.x;
    int wv = t >> 6, lane = t & 63, quad = lane >> 4, l15 = lane & 15;
    int n0 = blockIdx.x * 64;

    // prime W ping-pong prefetch (independent of embed compute)
    const short8* Wl = (const short8*)Wsw;
    short8 bq[2][4];
    #pragma unroll
    for (int ci = 0; ci < 4; ci++)
        bq[0][ci] = Wl[(size_t)(wv * 4 + ci) * 64 + lane];

    // compute embed tile -> As. thread handles row r, col-octet c8.
    #pragma unroll 2
    for (int i = 0; i < 8; i++) {
        int j = t + i * 256;
        int r = j >> 5;
        int c8 = j & 31;
        int n = n0 + r;
        unsigned o0 = 0, o1 = 0, o2 = 0, o3 = 0;
        if (n < N) {
            float xr[NODE_FEAT];
            #pragma unroll
            for (int k = 0; k < NODE_FEAT; k++) xr[k] = x[(size_t)n * NODE_FEAT + k];
            float4 a0 = *(const float4*)&embb[c8 * 8];
            float4 a1 = *(const float4*)&embb[c8 * 8 + 4];
            #pragma unroll
            for (int k = 0; k < NODE_FEAT; k++) {
                float4 w0 = *(const float4*)&embW[k * HIDDEN + c8 * 8];
                float4 w1 = *(const float4*)&embW[k * HIDDEN + c8 * 8 + 4];
                a0.x += xr[k] * w0.x; a0.y += xr[k] * w0.y;
                a0.z += xr[k] * w0.z; a0.w += xr[k] * w0.w;
                a1.x += xr[k] * w1.x; a1.y += xr[k] * w1.y;
                a1.z += xr[k] * w1.z; a1.w += xr[k] * w1.w;
            }
            o0 = (unsigned)f2bf(fmaxf(a0.x, 0.f)) | ((unsigned)f2bf(fmaxf(a0.y, 0.f)) << 16);
            o1 = (unsigned)f2bf(fmaxf(a0.z, 0.f)) | ((unsigned)f2bf(fmaxf(a0.w, 0.f)) << 16);
            o2 = (unsigned)f2bf(fmaxf(a1.x, 0.f)) | ((unsigned)f2bf(fmaxf(a1.y, 0.f)) << 16);
            o3 = (unsigned)f2bf(fmaxf(a1.z, 0.f)) | ((unsigned)f2bf(fmaxf(a1.w, 0.f)) << 16);
        }
        *(uint4*)&As[r][c8 * 8] = make_uint4(o0, o1, o2, o3);
    }
    __syncthreads();

    floatx4 acc[4][4];
    #pragma unroll
    for (int i = 0; i < 4; i++)
        #pragma unroll
        for (int j = 0; j < 4; j++)
            acc[i][j] = (floatx4){0.f, 0.f, 0.f, 0.f};

    #pragma unroll
    for (int ks = 0; ks < 8; ks++) {
        if (ks < 7) {
            #pragma unroll
            for (int ci = 0; ci < 4; ci++)
                bq[(ks + 1) & 1][ci] = Wl[(size_t)((ks + 1) * 16 + wv * 4 + ci) * 64 + lane];
        }
        short8 a[4];
        #pragma unroll
        for (int rt = 0; rt < 4; rt++)
            a[rt] = *(const short8*)&As[rt * 16 + l15][ks * 32 + quad * 8];
        #pragma unroll
        for (int rt = 0; rt < 4; rt++)
            #pragma unroll
            for (int ci = 0; ci < 4; ci++)
                acc[rt][ci] = __builtin_amdgcn_mfma_f32_16x16x32_bf16(a[rt], bq[ks & 1][ci], acc[rt][ci], 0, 0, 0);
    }

    __syncthreads();   // all A-fragment reads done; reuse As as C-buffer
    #pragma unroll
    for (int rt = 0; rt < 4; rt++) {
        #pragma unroll
        for (int ci = 0; ci < 4; ci++) {
            int col = (wv * 4 + ci) * 16 + l15;
            int rowb = rt * 16 + quad * 4;
            #pragma unroll
            for (int reg = 0; reg < 4; reg++)
                As[rowb + reg][col] = f2bf(acc[rt][ci][reg]);
        }
    }
    __syncthreads();
    #pragma unroll
    for (int i = 0; i < 8; i++) {
        int j = t + i * 256;
        int r = j >> 5;
        int c = j & 31;          // col-octet; slice = c>>2, within-slice octet = c&3
        int n = n0 + r;
        if (n < N)
            *(uint4*)&hwout[smb(c >> 2, n) + (c & 3) * 8] = *(const uint4*)&As[r][c * 8];
    }
}

// ---------------- hw = h @ W  (slice-major in/out; bf16 MFMA) ----------------
__global__ __launch_bounds__(256, 3) void gemm_mfma(const unsigned short* __restrict__ hin,
                                                    const unsigned short* __restrict__ Wsw,
                                                    unsigned short* __restrict__ hwout, int N) {
    __shared__ unsigned short As[64][264];
    int t = threadIdx.x;
    int wv = t >> 6, lane = t & 63, quad = lane >> 4, l15 = lane & 15;
    int n0 = blockIdx.x * 64;

    uint4 av[8];
    #pragma unroll
    for (int i = 0; i < 8; i++) {
        int j = t + i * 256;
        int r = j >> 5;
        int c = j & 31;
        int n = n0 + r;
        av[i] = make_uint4(0u, 0u, 0u, 0u);
        if (n < N) av[i] = *(const uint4*)&hin[smb(c >> 2, n) + (c & 3) * 8];
    }
    const short8* Wl = (const short8*)Wsw;
    short8 bq[2][4];
    #pragma unroll
    for (int ci = 0; ci < 4; ci++)
        bq[0][ci] = Wl[(size_t)(wv * 4 + ci) * 64 + lane];
    #pragma unroll
    for (int i = 0; i < 8; i++) {
        int j = t + i * 256;
        int r = j >> 5;
        int c = j & 31;
        *(uint4*)&As[r][c * 8] = av[i];
    }
    __syncthreads();

    floatx4 acc[4][4];
    #pragma unroll
    for (int i = 0; i < 4; i++)
        #pragma unroll
        for (int j = 0; j < 4; j++)
            acc[i][j] = (floatx4){0.f, 0.f, 0.f, 0.f};

    #pragma unroll
    for (int ks = 0; ks < 8; ks++) {
        if (ks < 7) {
            #pragma unroll
            for (int ci = 0; ci < 4; ci++)
                bq[(ks + 1) & 1][ci] = Wl[(size_t)((ks + 1) * 16 + wv * 4 + ci) * 64 + lane];
        }
        short8 a[4];
        #pragma unroll
        for (int rt = 0; rt < 4; rt++)
            a[rt] = *(const short8*)&As[rt * 16 + l15][ks * 32 + quad * 8];
        #pragma unroll
        for (int rt = 0; rt < 4; rt++)
            #pragma unroll
            for (int ci = 0; ci < 4; ci++)
                acc[rt][ci] = __builtin_amdgcn_mfma_f32_16x16x32_bf16(a[rt], bq[ks & 1][ci], acc[rt][ci], 0, 0, 0);
    }

    __syncthreads();
    #pragma unroll
    for (int rt = 0; rt < 4; rt++) {
        #pragma unroll
        for (int ci = 0; ci < 4; ci++) {
            int col = (wv * 4 + ci) * 16 + l15;
            int rowb = rt * 16 + quad * 4;
            #pragma unroll
            for (int reg = 0; reg < 4; reg++)
                As[rowb + reg][col] = f2bf(acc[rt][ci][reg]);
        }
    }
    __syncthreads();
    #pragma unroll
    for (int i = 0; i < 8; i++) {
        int j = t + i * 256;
        int r = j >> 5;
        int c = j & 31;
        int n = n0 + r;
        if (n < N)
            *(uint4*)&hwout[smb(c >> 2, n) + (c & 3) * 8] = *(const uint4*)&As[r][c * 8];
    }
}

// ---------------- XCD-sliced aggregation ----------------
// slice = blockIdx%8 -> (empirical round-robin) all blocks of slice s land on
// XCD s, whose gather working set hw[s][*][32] = 3.2 MB fits the 4 MB L2.
// Wave = 4 nodes x 16 lanes x 2 cols. Per-column edge accumulation order is
// identical to the previous kernel (bucket order, self+bias first).
__global__ __launch_bounds__(256) void agg_kernel(const unsigned short* __restrict__ hw,
                                                  const int* __restrict__ cnt,
                                                  const int* __restrict__ col_src,
                                                  const float* __restrict__ dinv,
                                                  const float* __restrict__ bias,
                                                  unsigned short* __restrict__ hout) {
    __shared__ uint2 sEdge[4][4][BUCKET];   // 8 KB: [wave][sub-node][edge]
    int t = threadIdx.x;
    int wv = t >> 6, lane = t & 63;
    int sub = lane >> 4, cl = lane & 15;
    int slice = blockIdx.x & 7;
    int chunk = blockIdx.x >> 3;
    int n = chunk * 16 + wv * 4 + sub;      // 3125*16 == 50000: always in range
    float dn = dinv[n];
    int deg = cnt[n]; if (deg > BUCKET) deg = BUCKET;

    #pragma unroll
    for (int r = 0; r < 4; r++) {
        int e = cl + r * 16;
        if (e < deg) {
            int s = col_src[n * BUCKET + e];
            float nr = dinv[s] * dn;
            unsigned nrb; __builtin_memcpy(&nrb, &nr, 4);
            sEdge[wv][sub][e] = make_uint2((unsigned)s, nrb);
        }
    }

    size_t sb = smb(slice, n);
    unsigned su = *(const unsigned*)&hw[sb + 2 * cl];
    float2 b2 = *(const float2*)&bias[slice * 32 + 2 * cl];
    float selfc = dn * dn;
    float a0 = bf2f(su & 0xFFFFu) * selfc + b2.x;
    float a1 = bf2f(su >> 16)     * selfc + b2.y;

    size_t slice_base = (size_t)slice * N_NODES;
    // same-wave LDS write->read: ordered by lgkmcnt, no barrier needed
    for (int i = 0; i < deg; i++) {
        uint2 p = sEdge[wv][sub][i];
        float nr; __builtin_memcpy(&nr, &p.y, 4);
        unsigned u = *(const unsigned*)&hw[(slice_base + p.x) * 32 + 2 * cl];
        a0 += nr * bf2f(u & 0xFFFFu);
        a1 += nr * bf2f(u >> 16);
    }
    unsigned o = (unsigned)f2bf(fmaxf(a0, 0.0f)) | ((unsigned)f2bf(fmaxf(a1, 0.0f)) << 16);
    *(unsigned*)&hout[sb + 2 * cl] = o;
}

// ---------------- XCD-sliced layer-4 agg fused with output dot (no atomics) ----------------
// Writes per-(node,slice) partial dots; finalize sums 8 partials per node.
__global__ __launch_bounds__(256) void agg_dot_kernel(const unsigned short* __restrict__ hw,
                                                      const int* __restrict__ cnt,
                                                      const int* __restrict__ col_src,
                                                      const float* __restrict__ dinv,
                                                      const float* __restrict__ bias,
                                                      const float* __restrict__ outW,
                                                      float* __restrict__ dotp) {
    __shared__ uint2 sEdge[4][4][BUCKET];
    int t = threadIdx.x;
    int wv = t >> 6, lane = t & 63;
    int sub = lane >> 4, cl = lane & 15;
    int slice = blockIdx.x & 7;
    int chunk = blockIdx.x >> 3;
    int n = chunk * 16 + wv * 4 + sub;
    float dn = dinv[n];
    int deg = cnt[n]; if (deg > BUCKET) deg = BUCKET;

    #pragma unroll
    for (int r = 0; r < 4; r++) {
        int e = cl + r * 16;
        if (e < deg) {
            int s = col_src[n * BUCKET + e];
            float nr = dinv[s] * dn;
            unsigned nrb; __builtin_memcpy(&nrb, &nr, 4);
            sEdge[wv][sub][e] = make_uint2((unsigned)s, nrb);
        }
    }

    size_t sb = smb(slice, n);
    unsigned su = *(const unsigned*)&hw[sb + 2 * cl];
    float2 b2 = *(const float2*)&bias[slice * 32 + 2 * cl];
    float selfc = dn * dn;
    float a0 = bf2f(su & 0xFFFFu) * selfc + b2.x;
    float a1 = bf2f(su >> 16)     * selfc + b2.y;

    size_t slice_base = (size_t)slice * N_NODES;
    for (int i = 0; i < deg; i++) {
        uint2 p = sEdge[wv][sub][i];
        float nr; __builtin_memcpy(&nr, &p.y, 4);
        unsigned u = *(const unsigned*)&hw[(slice_base + p.x) * 32 + 2 * cl];
        a0 += nr * bf2f(u & 0xFFFFu);
        a1 += nr * bf2f(u >> 16);
    }
    float2 w2 = *(const float2*)&outW[slice * 32 + 2 * cl];
    float dot = fmaxf(a0, 0.0f) * w2.x + fmaxf(a1, 0.0f) * w2.y;
    #pragma unroll
    for (int off = 8; off > 0; off >>= 1) dot += __shfl_xor(dot, off, 64);  // within 16-lane group
    if (cl == 0) dotp[(size_t)n * NSLICE + slice] = dot;
}

// ---------------- segment mean over sorted batch ranges (one wave per graph) ----------------
__global__ __launch_bounds__(64) void finalize_kernel(const float* __restrict__ dotp,
                                                      const int* __restrict__ gstart,
                                                      const float* __restrict__ outb,
                                                      float* __restrict__ out) {
    int g = blockIdx.x;
    int lane = threadIdx.x;
    int s = gstart[g], e = gstart[g + 1];
    float acc = 0.0f;
    for (size_t i = (size_t)s * NSLICE + lane; i < (size_t)e * NSLICE; i += 64) acc += dotp[i];
    #pragma unroll
    for (int off = 32; off > 0; off >>= 1) acc += __shfl_xor(acc, off, 64);
    if (lane == 0) out[g] = acc / fmaxf((float)(e - s), 1.0f) + outb[0];
}

extern "C" void kernel_launch(void* const* d_in, const int* in_sizes, int n_in,
                              void* d_out, int out_size, void* d_ws, size_t ws_size,
                              hipStream_t stream) {
    const float* x     = (const float*)d_in[0];
    const int*   edge  = (const int*)d_in[1];
    const int*   src   = edge;
    const int*   dst   = edge + N_EDGES;
    const int*   batch = (const int*)d_in[2];
    const float* embW  = (const float*)d_in[3];
    const float* embb  = (const float*)d_in[4];
    const float* convW = (const float*)d_in[5];
    const float* convb = (const float*)d_in[6];
    const float* outW  = (const float*)d_in[7];
    const float* outb  = (const float*)d_in[8];
    float* out = (float*)d_out;

    // workspace layout
    char* ws = (char*)d_ws;
    size_t off = 0;
    auto take = [&](size_t bytes) { char* p = ws + off; off += (bytes + 255) & ~(size_t)255; return p; };
    int*   cnt     = (int*)  take((size_t)N_NODES * 4);
    int*   col_src = (int*)  take((size_t)N_NODES * BUCKET * 4);           // 12.8 MB buckets
    float* dinv    = (float*)take((size_t)N_NODES * 4);
    int*   gstart  = (int*)  take((size_t)(N_GRAPHS + 1) * 4);
    float* dotp    = (float*)take((size_t)N_NODES * NSLICE * 4);           // 1.6 MB partial dots
    unsigned short* Wsw = (unsigned short*)take((size_t)LAYERS * 8 * 16 * 64 * 8 * 2); // 512 KB
    unsigned short* h0  = (unsigned short*)take((size_t)N_NODES * HIDDEN * 2);
    unsigned short* h1  = (unsigned short*)take((size_t)N_NODES * HIDDEN * 2);

    hipMemsetAsync(cnt, 0, (size_t)N_NODES * 4, stream);

    packW_kernel<<<128, 256, 0, stream>>>(convW, Wsw);
    fillb_kernel<<<(N_EDGES + 255) / 256, 256, 0, stream>>>(src, dst, cnt, col_src, N_EDGES);
    aux_kernel<<<(N_NODES + N_GRAPHS + 1 + 255) / 256, 256, 0, stream>>>(cnt, dinv, batch, gstart);

    int nblk = (N_NODES + 63) / 64;
    int ablk = (N_NODES / 16) * NSLICE;   // 3125 node-chunks x 8 slices = 25000

    // layer 1: fused embed + transform
    embed_gemm<<<nblk, 256, 0, stream>>>(x, embW, embb, Wsw, h1, N_NODES);
    agg_kernel<<<ablk, 256, 0, stream>>>(h1, cnt, col_src, dinv, convb + 0 * HIDDEN, h0);
    // layers 2..3
    gemm_mfma<<<nblk, 256, 0, stream>>>(h0, Wsw + (size_t)1 * 65536, h1, N_NODES);
    agg_kernel<<<ablk, 256, 0, stream>>>(h1, cnt, col_src, dinv, convb + 1 * HIDDEN, h0);
    gemm_mfma<<<nblk, 256, 0, stream>>>(h0, Wsw + (size_t)2 * 65536, h1, N_NODES);
    agg_kernel<<<ablk, 256, 0, stream>>>(h1, cnt, col_src, dinv, convb + 2 * HIDDEN, h0);
    // layer 4: transform, then sliced agg fused with the output head
    gemm_mfma<<<nblk, 256, 0, stream>>>(h0, Wsw + (size_t)3 * 65536, h1, N_NODES);
    agg_dot_kernel<<<ablk, 256, 0, stream>>>(h1, cnt, col_src, dinv, convb + 3 * HIDDEN, outW, dotp);

    finalize_kernel<<<N_GRAPHS, 64, 0, stream>>>(dotp, gstart, outb, out);
}

// Round 6
// 476.643 us; speedup vs baseline: 1.0873x; 1.0873x over previous
//
#include <hip/hip_runtime.h>

#define N_NODES 50000
#define N_EDGES 800000
#define N_GRAPHS 512
#define HIDDEN 256
#define NODE_FEAT 9
#define LAYERS 4
#define BUCKET 64     // max degree capacity (mean 16, max ~35 for uniform random)
#define NSLICE 8      // 8 column slices of 32 -> one per XCD (L2-resident: 3.2 MB)

typedef float floatx4 __attribute__((ext_vector_type(4)));
typedef short short8 __attribute__((ext_vector_type(8)));

__device__ __forceinline__ float bf2f(unsigned u) {
    unsigned v = u << 16;
    float f;
    __builtin_memcpy(&f, &v, 4);
    return f;
}
__device__ __forceinline__ unsigned short f2bf(float f) {
    unsigned v;
    __builtin_memcpy(&v, &f, 4);
    v += 0x7FFFu + ((v >> 16) & 1u);   // round-to-nearest-even
    return (unsigned short)(v >> 16);
}
// slice-major element base: h[s][n][0..31], in ushorts
__device__ __forceinline__ size_t smb(int s, int n) {
    return ((size_t)s * N_NODES + (size_t)n) * 32;
}

// ---------------- one-pass bucketed CSR build ----------------
__global__ void fillb_kernel(const int* __restrict__ src, const int* __restrict__ dst,
                             int* __restrict__ cnt, int* __restrict__ col_src, int E) {
    int e = blockIdx.x * blockDim.x + threadIdx.x;
    if (e < E) {
        int d = dst[e];
        int pos = atomicAdd(&cnt[d], 1);
        if (pos < BUCKET) col_src[d * BUCKET + pos] = src[e];
    }
}

// ---------------- combined aux: dinv + graph boundary search ----------------
__global__ __launch_bounds__(256) void aux_kernel(const int* __restrict__ cnt,
                                                  float* __restrict__ dinv,
                                                  const int* __restrict__ batch,
                                                  int* __restrict__ gstart) {
    int i = blockIdx.x * 256 + threadIdx.x;
    if (i < N_NODES) dinv[i] = rsqrtf((float)(cnt[i] + 1));   // +1 self loop
    int g = i - N_NODES;
    if (g >= 0 && g <= N_GRAPHS) {
        if (g == N_GRAPHS) { gstart[g] = N_NODES; return; }
        int lo = 0, hi = N_NODES;
        while (lo < hi) {
            int mid = (lo + hi) >> 1;
            if (batch[mid] < g) lo = mid + 1; else hi = mid;
        }
        gstart[g] = lo;   // first node with batch[n] >= g
    }
}

// ---------------- edge prep: interleave (src, norm) once; reused by all 4 aggs x 8 slices ----------------
__global__ __launch_bounds__(256) void eprep_kernel(const int* __restrict__ cnt,
                                                    const int* __restrict__ col_src,
                                                    const float* __restrict__ dinv,
                                                    uint2* __restrict__ esrc) {
    int i = blockIdx.x * 256 + threadIdx.x;   // over N_NODES*BUCKET
    int n = i >> 6, e = i & 63;
    int deg = cnt[n]; if (deg > BUCKET) deg = BUCKET;
    if (e < deg) {
        int s = col_src[i];
        float nr = dinv[s] * dinv[n];
        unsigned nrb; __builtin_memcpy(&nrb, &nr, 4);
        esrc[i] = make_uint2((unsigned)s, nrb);
    }
}

// ---------------- W pre-pack into MFMA B-fragment layout (bf16) ----------------
__global__ __launch_bounds__(256) void packW_kernel(const float* __restrict__ W,
                                                    unsigned short* __restrict__ Wsw) {
    int idx = blockIdx.x * 256 + threadIdx.x;   // 0..32767
    int lane = idx & 63;
    int ct   = (idx >> 6) & 15;
    int ks   = (idx >> 10) & 7;
    int l    = idx >> 13;
    int n = ct * 16 + (lane & 15);
    int kbase = ks * 32 + (lane >> 4) * 8;
    const float* Wl = W + (size_t)l * HIDDEN * HIDDEN;
    alignas(16) unsigned short tmp[8];
    #pragma unroll
    for (int j = 0; j < 8; j++)
        tmp[j] = f2bf(Wl[(size_t)(kbase + j) * HIDDEN + n]);
    *(uint4*)&Wsw[(size_t)idx * 8] = *(const uint4*)tmp;
}

// ---------------- fused embed + gemm1 (slice-coherent C-store) ----------------
__global__ __launch_bounds__(256, 3) void embed_gemm(const float* __restrict__ x,
                                                     const float* __restrict__ embW,
                                                     const float* __restrict__ embb,
                                                     const unsigned short* __restrict__ Wsw,
                                                     unsigned short* __restrict__ hwout, int N) {
    __shared__ unsigned short As[64][264];   // +8 pad; reused as C-buffer in epilogue
    int t = threadIdx.x;
    int wv = t >> 6, lane = t & 63, quad = lane >> 4, l15 = lane & 15;
    int n0 = blockIdx.x * 64;

    // prime W ping-pong prefetch (independent of embed compute)
    const short8* Wl = (const short8*)Wsw;
    short8 bq[2][4];
    #pragma unroll
    for (int ci = 0; ci < 4; ci++)
        bq[0][ci] = Wl[(size_t)(wv * 4 + ci) * 64 + lane];

    // compute embed tile -> As. thread handles row r, col-octet c8.
    #pragma unroll 2
    for (int i = 0; i < 8; i++) {
        int j = t + i * 256;
        int r = j >> 5;
        int c8 = j & 31;
        int n = n0 + r;
        unsigned o0 = 0, o1 = 0, o2 = 0, o3 = 0;
        if (n < N) {
            float xr[NODE_FEAT];
            #pragma unroll
            for (int k = 0; k < NODE_FEAT; k++) xr[k] = x[(size_t)n * NODE_FEAT + k];
            float4 a0 = *(const float4*)&embb[c8 * 8];
            float4 a1 = *(const float4*)&embb[c8 * 8 + 4];
            #pragma unroll
            for (int k = 0; k < NODE_FEAT; k++) {
                float4 w0 = *(const float4*)&embW[k * HIDDEN + c8 * 8];
                float4 w1 = *(const float4*)&embW[k * HIDDEN + c8 * 8 + 4];
                a0.x += xr[k] * w0.x; a0.y += xr[k] * w0.y;
                a0.z += xr[k] * w0.z; a0.w += xr[k] * w0.w;
                a1.x += xr[k] * w1.x; a1.y += xr[k] * w1.y;
                a1.z += xr[k] * w1.z; a1.w += xr[k] * w1.w;
            }
            o0 = (unsigned)f2bf(fmaxf(a0.x, 0.f)) | ((unsigned)f2bf(fmaxf(a0.y, 0.f)) << 16);
            o1 = (unsigned)f2bf(fmaxf(a0.z, 0.f)) | ((unsigned)f2bf(fmaxf(a0.w, 0.f)) << 16);
            o2 = (unsigned)f2bf(fmaxf(a1.x, 0.f)) | ((unsigned)f2bf(fmaxf(a1.y, 0.f)) << 16);
            o3 = (unsigned)f2bf(fmaxf(a1.z, 0.f)) | ((unsigned)f2bf(fmaxf(a1.w, 0.f)) << 16);
        }
        *(uint4*)&As[r][c8 * 8] = make_uint4(o0, o1, o2, o3);
    }
    __syncthreads();

    floatx4 acc[4][4];
    #pragma unroll
    for (int i = 0; i < 4; i++)
        #pragma unroll
        for (int j = 0; j < 4; j++)
            acc[i][j] = (floatx4){0.f, 0.f, 0.f, 0.f};

    #pragma unroll
    for (int ks = 0; ks < 8; ks++) {
        if (ks < 7) {
            #pragma unroll
            for (int ci = 0; ci < 4; ci++)
                bq[(ks + 1) & 1][ci] = Wl[(size_t)((ks + 1) * 16 + wv * 4 + ci) * 64 + lane];
        }
        short8 a[4];
        #pragma unroll
        for (int rt = 0; rt < 4; rt++)
            a[rt] = *(const short8*)&As[rt * 16 + l15][ks * 32 + quad * 8];
        #pragma unroll
        for (int rt = 0; rt < 4; rt++)
            #pragma unroll
            for (int ci = 0; ci < 4; ci++)
                acc[rt][ci] = __builtin_amdgcn_mfma_f32_16x16x32_bf16(a[rt], bq[ks & 1][ci], acc[rt][ci], 0, 0, 0);
    }

    __syncthreads();   // all A-fragment reads done; reuse As as C-buffer
    #pragma unroll
    for (int rt = 0; rt < 4; rt++) {
        #pragma unroll
        for (int ci = 0; ci < 4; ci++) {
            int col = (wv * 4 + ci) * 16 + l15;
            int rowb = rt * 16 + quad * 4;
            #pragma unroll
            for (int reg = 0; reg < 4; reg++)
                As[rowb + reg][col] = f2bf(acc[rt][ci][reg]);
        }
    }
    __syncthreads();
    // slice-coherent store: iteration i = slice i; 256 threads cover 64 rows x 4
    // octets = one contiguous 4 KB segment of h[s][n0..n0+63][*]
    #pragma unroll
    for (int i = 0; i < 8; i++) {
        int r = t >> 2;
        int oct = t & 3;
        int n = n0 + r;
        if (n < N)
            *(uint4*)&hwout[smb(i, n) + oct * 8] = *(const uint4*)&As[r][i * 32 + oct * 8];
    }
}

// ---------------- hw = h @ W  (slice-coherent staging + store; bf16 MFMA) ----------------
__global__ __launch_bounds__(256, 3) void gemm_mfma(const unsigned short* __restrict__ hin,
                                                    const unsigned short* __restrict__ Wsw,
                                                    unsigned short* __restrict__ hwout, int N) {
    __shared__ unsigned short As[64][264];
    int t = threadIdx.x;
    int wv = t >> 6, lane = t & 63, quad = lane >> 4, l15 = lane & 15;
    int n0 = blockIdx.x * 64;
    int sr = t >> 2;       // staging row 0..63
    int soct = t & 3;      // staging octet 0..3

    // stage: iteration i reads slice i, rows n0..n0+63 -- 4 KB contiguous
    uint4 av[8];
    #pragma unroll
    for (int i = 0; i < 8; i++) {
        int n = n0 + sr;
        av[i] = make_uint4(0u, 0u, 0u, 0u);
        if (n < N) av[i] = *(const uint4*)&hin[smb(i, n) + soct * 8];
    }
    const short8* Wl = (const short8*)Wsw;
    short8 bq[2][4];
    #pragma unroll
    for (int ci = 0; ci < 4; ci++)
        bq[0][ci] = Wl[(size_t)(wv * 4 + ci) * 64 + lane];
    #pragma unroll
    for (int i = 0; i < 8; i++)
        *(uint4*)&As[sr][i * 32 + soct * 8] = av[i];
    __syncthreads();

    floatx4 acc[4][4];
    #pragma unroll
    for (int i = 0; i < 4; i++)
        #pragma unroll
        for (int j = 0; j < 4; j++)
            acc[i][j] = (floatx4){0.f, 0.f, 0.f, 0.f};

    #pragma unroll
    for (int ks = 0; ks < 8; ks++) {
        if (ks < 7) {
            #pragma unroll
            for (int ci = 0; ci < 4; ci++)
                bq[(ks + 1) & 1][ci] = Wl[(size_t)((ks + 1) * 16 + wv * 4 + ci) * 64 + lane];
        }
        short8 a[4];
        #pragma unroll
        for (int rt = 0; rt < 4; rt++)
            a[rt] = *(const short8*)&As[rt * 16 + l15][ks * 32 + quad * 8];
        #pragma unroll
        for (int rt = 0; rt < 4; rt++)
            #pragma unroll
            for (int ci = 0; ci < 4; ci++)
                acc[rt][ci] = __builtin_amdgcn_mfma_f32_16x16x32_bf16(a[rt], bq[ks & 1][ci], acc[rt][ci], 0, 0, 0);
    }

    __syncthreads();
    #pragma unroll
    for (int rt = 0; rt < 4; rt++) {
        #pragma unroll
        for (int ci = 0; ci < 4; ci++) {
            int col = (wv * 4 + ci) * 16 + l15;
            int rowb = rt * 16 + quad * 4;
            #pragma unroll
            for (int reg = 0; reg < 4; reg++)
                As[rowb + reg][col] = f2bf(acc[rt][ci][reg]);
        }
    }
    __syncthreads();
    #pragma unroll
    for (int i = 0; i < 8; i++) {
        int n = n0 + sr;
        if (n < N)
            *(uint4*)&hwout[smb(i, n) + soct * 8] = *(const uint4*)&As[sr][i * 32 + soct * 8];
    }
}

// ---------------- XCD-sliced aggregation, latency-pipelined ----------------
// slice = blockIdx&7 -> per-XCD gather set hw[s][*][32] = 3.2 MB (L2-fit).
// Wave = 4 subnodes x 16 lanes x 2 cols. Edge metadata staged from the
// precomputed (src,nr) array with one coalesced 8-B load per edge; hot loop
// unrolled x4 so each subgroup keeps 4 gathers in flight (vs 1 in R5).
// Per-column FP accumulation order identical to all previous versions.
__global__ __launch_bounds__(256) void agg_kernel(const unsigned short* __restrict__ hw,
                                                  const int* __restrict__ cnt,
                                                  const uint2* __restrict__ esrc,
                                                  const float* __restrict__ dinv,
                                                  const float* __restrict__ bias,
                                                  unsigned short* __restrict__ hout) {
    __shared__ uint2 sEdge[4][4][BUCKET];   // 8 KB: [wave][sub-node][edge]
    int t = threadIdx.x;
    int wv = t >> 6, lane = t & 63;
    int sub = lane >> 4, cl = lane & 15;
    int slice = blockIdx.x & 7;
    int chunk = blockIdx.x >> 3;
    int n = chunk * 16 + wv * 4 + sub;      // 3125*16 == 50000: always in range
    float dn = dinv[n];
    int deg = cnt[n]; if (deg > BUCKET) deg = BUCKET;

    #pragma unroll
    for (int r = 0; r < 4; r++) {
        int e = cl + r * 16;
        if (e < deg) sEdge[wv][sub][e] = esrc[n * BUCKET + e];
    }

    const unsigned short* hws = hw + smb(slice, 0);   // slice base
    const unsigned short* hwl = hws + 2 * cl;         // per-lane column base

    unsigned su = *(const unsigned*)(hws + (size_t)n * 32 + 2 * cl);
    float2 b2 = *(const float2*)&bias[slice * 32 + 2 * cl];
    float selfc = dn * dn;
    float a0 = bf2f(su & 0xFFFFu) * selfc + b2.x;
    float a1 = bf2f(su >> 16)     * selfc + b2.y;

    // same-wave LDS write->read: ordered by lgkmcnt, no barrier needed
    int i = 0;
    for (; i + 4 <= deg; i += 4) {
        uint2 p0 = sEdge[wv][sub][i];
        uint2 p1 = sEdge[wv][sub][i + 1];
        uint2 p2 = sEdge[wv][sub][i + 2];
        uint2 p3 = sEdge[wv][sub][i + 3];
        unsigned u0 = *(const unsigned*)(hwl + (size_t)p0.x * 32);
        unsigned u1 = *(const unsigned*)(hwl + (size_t)p1.x * 32);
        unsigned u2 = *(const unsigned*)(hwl + (size_t)p2.x * 32);
        unsigned u3 = *(const unsigned*)(hwl + (size_t)p3.x * 32);
        float n0_, n1_, n2_, n3_;
        __builtin_memcpy(&n0_, &p0.y, 4);
        __builtin_memcpy(&n1_, &p1.y, 4);
        __builtin_memcpy(&n2_, &p2.y, 4);
        __builtin_memcpy(&n3_, &p3.y, 4);
        a0 += n0_ * bf2f(u0 & 0xFFFFu); a1 += n0_ * bf2f(u0 >> 16);
        a0 += n1_ * bf2f(u1 & 0xFFFFu); a1 += n1_ * bf2f(u1 >> 16);
        a0 += n2_ * bf2f(u2 & 0xFFFFu); a1 += n2_ * bf2f(u2 >> 16);
        a0 += n3_ * bf2f(u3 & 0xFFFFu); a1 += n3_ * bf2f(u3 >> 16);
    }
    for (; i < deg; i++) {
        uint2 p = sEdge[wv][sub][i];
        float nr; __builtin_memcpy(&nr, &p.y, 4);
        unsigned u = *(const unsigned*)(hwl + (size_t)p.x * 32);
        a0 += nr * bf2f(u & 0xFFFFu);
        a1 += nr * bf2f(u >> 16);
    }
    unsigned o = (unsigned)f2bf(fmaxf(a0, 0.0f)) | ((unsigned)f2bf(fmaxf(a1, 0.0f)) << 16);
    *(unsigned*)&hout[smb(slice, n) + 2 * cl] = o;
}

// ---------------- XCD-sliced layer-4 agg fused with output dot (no atomics) ----------------
__global__ __launch_bounds__(256) void agg_dot_kernel(const unsigned short* __restrict__ hw,
                                                      const int* __restrict__ cnt,
                                                      const uint2* __restrict__ esrc,
                                                      const float* __restrict__ dinv,
                                                      const float* __restrict__ bias,
                                                      const float* __restrict__ outW,
                                                      float* __restrict__ dotp) {
    __shared__ uint2 sEdge[4][4][BUCKET];
    int t = threadIdx.x;
    int wv = t >> 6, lane = t & 63;
    int sub = lane >> 4, cl = lane & 15;
    int slice = blockIdx.x & 7;
    int chunk = blockIdx.x >> 3;
    int n = chunk * 16 + wv * 4 + sub;
    float dn = dinv[n];
    int deg = cnt[n]; if (deg > BUCKET) deg = BUCKET;

    #pragma unroll
    for (int r = 0; r < 4; r++) {
        int e = cl + r * 16;
        if (e < deg) sEdge[wv][sub][e] = esrc[n * BUCKET + e];
    }

    const unsigned short* hws = hw + smb(slice, 0);
    const unsigned short* hwl = hws + 2 * cl;

    unsigned su = *(const unsigned*)(hws + (size_t)n * 32 + 2 * cl);
    float2 b2 = *(const float2*)&bias[slice * 32 + 2 * cl];
    float selfc = dn * dn;
    float a0 = bf2f(su & 0xFFFFu) * selfc + b2.x;
    float a1 = bf2f(su >> 16)     * selfc + b2.y;

    int i = 0;
    for (; i + 4 <= deg; i += 4) {
        uint2 p0 = sEdge[wv][sub][i];
        uint2 p1 = sEdge[wv][sub][i + 1];
        uint2 p2 = sEdge[wv][sub][i + 2];
        uint2 p3 = sEdge[wv][sub][i + 3];
        unsigned u0 = *(const unsigned*)(hwl + (size_t)p0.x * 32);
        unsigned u1 = *(const unsigned*)(hwl + (size_t)p1.x * 32);
        unsigned u2 = *(const unsigned*)(hwl + (size_t)p2.x * 32);
        unsigned u3 = *(const unsigned*)(hwl + (size_t)p3.x * 32);
        float n0_, n1_, n2_, n3_;
        __builtin_memcpy(&n0_, &p0.y, 4);
        __builtin_memcpy(&n1_, &p1.y, 4);
        __builtin_memcpy(&n2_, &p2.y, 4);
        __builtin_memcpy(&n3_, &p3.y, 4);
        a0 += n0_ * bf2f(u0 & 0xFFFFu); a1 += n0_ * bf2f(u0 >> 16);
        a0 += n1_ * bf2f(u1 & 0xFFFFu); a1 += n1_ * bf2f(u1 >> 16);
        a0 += n2_ * bf2f(u2 & 0xFFFFu); a1 += n2_ * bf2f(u2 >> 16);
        a0 += n3_ * bf2f(u3 & 0xFFFFu); a1 += n3_ * bf2f(u3 >> 16);
    }
    for (; i < deg; i++) {
        uint2 p = sEdge[wv][sub][i];
        float nr; __builtin_memcpy(&nr, &p.y, 4);
        unsigned u = *(const unsigned*)(hwl + (size_t)p.x * 32);
        a0 += nr * bf2f(u & 0xFFFFu);
        a1 += nr * bf2f(u >> 16);
    }
    float2 w2 = *(const float2*)&outW[slice * 32 + 2 * cl];
    float dot = fmaxf(a0, 0.0f) * w2.x + fmaxf(a1, 0.0f) * w2.y;
    #pragma unroll
    for (int off = 8; off > 0; off >>= 1) dot += __shfl_xor(dot, off, 64);  // within 16-lane group
    if (cl == 0) dotp[(size_t)n * NSLICE + slice] = dot;
}

// ---------------- segment mean over sorted batch ranges (one wave per graph) ----------------
__global__ __launch_bounds__(64) void finalize_kernel(const float* __restrict__ dotp,
                                                      const int* __restrict__ gstart,
                                                      const float* __restrict__ outb,
                                                      float* __restrict__ out) {
    int g = blockIdx.x;
    int lane = threadIdx.x;
    int s = gstart[g], e = gstart[g + 1];
    float acc = 0.0f;
    for (size_t i = (size_t)s * NSLICE + lane; i < (size_t)e * NSLICE; i += 64) acc += dotp[i];
    #pragma unroll
    for (int off = 32; off > 0; off >>= 1) acc += __shfl_xor(acc, off, 64);
    if (lane == 0) out[g] = acc / fmaxf((float)(e - s), 1.0f) + outb[0];
}

extern "C" void kernel_launch(void* const* d_in, const int* in_sizes, int n_in,
                              void* d_out, int out_size, void* d_ws, size_t ws_size,
                              hipStream_t stream) {
    const float* x     = (const float*)d_in[0];
    const int*   edge  = (const int*)d_in[1];
    const int*   src   = edge;
    const int*   dst   = edge + N_EDGES;
    const int*   batch = (const int*)d_in[2];
    const float* embW  = (const float*)d_in[3];
    const float* embb  = (const float*)d_in[4];
    const float* convW = (const float*)d_in[5];
    const float* convb = (const float*)d_in[6];
    const float* outW  = (const float*)d_in[7];
    const float* outb  = (const float*)d_in[8];
    float* out = (float*)d_out;

    // workspace layout
    char* ws = (char*)d_ws;
    size_t off = 0;
    auto take = [&](size_t bytes) { char* p = ws + off; off += (bytes + 255) & ~(size_t)255; return p; };
    int*   cnt     = (int*)  take((size_t)N_NODES * 4);
    int*   col_src = (int*)  take((size_t)N_NODES * BUCKET * 4);           // 12.8 MB buckets
    uint2* esrc    = (uint2*)take((size_t)N_NODES * BUCKET * 8);           // 25.6 MB (src,nr)
    float* dinv    = (float*)take((size_t)N_NODES * 4);
    int*   gstart  = (int*)  take((size_t)(N_GRAPHS + 1) * 4);
    float* dotp    = (float*)take((size_t)N_NODES * NSLICE * 4);           // 1.6 MB partial dots
    unsigned short* Wsw = (unsigned short*)take((size_t)LAYERS * 8 * 16 * 64 * 8 * 2); // 512 KB
    unsigned short* h0  = (unsigned short*)take((size_t)N_NODES * HIDDEN * 2);
    unsigned short* h1  = (unsigned short*)take((size_t)N_NODES * HIDDEN * 2);

    hipMemsetAsync(cnt, 0, (size_t)N_NODES * 4, stream);

    packW_kernel<<<128, 256, 0, stream>>>(convW, Wsw);
    fillb_kernel<<<(N_EDGES + 255) / 256, 256, 0, stream>>>(src, dst, cnt, col_src, N_EDGES);
    aux_kernel<<<(N_NODES + N_GRAPHS + 1 + 255) / 256, 256, 0, stream>>>(cnt, dinv, batch, gstart);
    eprep_kernel<<<(N_NODES * BUCKET) / 256, 256, 0, stream>>>(cnt, col_src, dinv, esrc);

    int nblk = (N_NODES + 63) / 64;
    int ablk = (N_NODES / 16) * NSLICE;   // 3125 node-chunks x 8 slices = 25000

    // layer 1: fused embed + transform
    embed_gemm<<<nblk, 256, 0, stream>>>(x, embW, embb, Wsw, h1, N_NODES);
    agg_kernel<<<ablk, 256, 0, stream>>>(h1, cnt, esrc, dinv, convb + 0 * HIDDEN, h0);
    // layers 2..3
    gemm_mfma<<<nblk, 256, 0, stream>>>(h0, Wsw + (size_t)1 * 65536, h1, N_NODES);
    agg_kernel<<<ablk, 256, 0, stream>>>(h1, cnt, esrc, dinv, convb + 1 * HIDDEN, h0);
    gemm_mfma<<<nblk, 256, 0, stream>>>(h0, Wsw + (size_t)2 * 65536, h1, N_NODES);
    agg_kernel<<<ablk, 256, 0, stream>>>(h1, cnt, esrc, dinv, convb + 2 * HIDDEN, h0);
    // layer 4: transform, then sliced agg fused with the output head
    gemm_mfma<<<nblk, 256, 0, stream>>>(h0, Wsw + (size_t)3 * 65536, h1, N_NODES);
    agg_dot_kernel<<<ablk, 256, 0, stream>>>(h1, cnt, esrc, dinv, convb + 3 * HIDDEN, outW, dotp);

    finalize_kernel<<<N_GRAPHS, 64, 0, stream>>>(dotp, gstart, outb, out);
}